// Round 9
// baseline (35.975 us; speedup 1.0000x reference)
//
#include <hip/hip_runtime.h>
#include <stdint.h>
#include <math.h>

#define NN 8192
#define DD 128
#define NB 64                    // 8192/128 tiles per dim
#define NBLK (NB * (NB + 1) / 2) // 2080 upper-triangular tile blocks
#define NC 32                    // classes
#define NPB 256                  // prep blocks (= class partial blocks)
#define RPB 32                   // rows per prep block
#define TOTBLK (NBLK + NC)       // fused loss grid (2112 = 8 * 264)
#define SCALE (2.0f / ((float)NN * (float)(NN - 1)))

typedef __attribute__((ext_vector_type(8))) short short8;
typedef __attribute__((ext_vector_type(4))) float f32x4;

__device__ __forceinline__ unsigned short f2bf_rne(float x) {
    union { float f; uint32_t u; } v; v.f = x;
    uint32_t r = v.u + 0x7FFFu + ((v.u >> 16) & 1u);
    return (unsigned short)(r >> 16);
}

// bf16 fragment-major layout (for mfma_f32_16x16x32_bf16):
// panel = row>>4 (16 rows, 4096 B); byte(row,k) = panel*4096 + (k>>3)*256 + (row&15)*16
// -> fragment read for (panel, ks): lane l reads 16 B at
//    panel*4096 + ks*1024 + (l>>4)*256 + (l&15)*16   (contiguous 1 KB per wave)
// The LDS copy of a panel range is byte-identical to global -> global_load_lds
// staging is a pure linear copy (wave-uniform LDS base + lane*16; per-lane src).

// prep: 256 blocks x 32 rows. bf16 cast into a2y (= -2y, exact exp+1 bit trick)
// and ybf (= y), frag-major + exact fp32 row norms + per-block per-class partial
// sums (4 LDS copies, atomic-free). Zeroes out[0].
__global__ __launch_bounds__(256) void prep_kernel(const float* __restrict__ ys,
                                                   const int* __restrict__ lab,
                                                   unsigned short* __restrict__ a2y,
                                                   unsigned short* __restrict__ ybf,
                                                   float* __restrict__ sq,
                                                   float* __restrict__ clspart,
                                                   float* __restrict__ out) {
    int b = blockIdx.x, t = threadIdx.x;
    __shared__ float cls[4][NC][DD];   // 64 KB
    __shared__ int slab[RPB];

#pragma unroll
    for (int i = 0; i < 16; ++i) ((float4*)cls)[i * 256 + t] = make_float4(0.f, 0.f, 0.f, 0.f);
    if (t < RPB) slab[t] = lab[b * RPB + t];

#pragma unroll
    for (int u = 0; u < 2; ++u) {
        int rloc = (t >> 4) + u * 16;   // 0..31
        int c8 = t & 15;                // 8-elem k-chunk within row
        int row = b * RPB + rloc;
        const float* base = ys + (size_t)row * DD + c8 * 8;
        float4 v0 = *(const float4*)base;
        float4 v1 = *(const float4*)(base + 4);
        uint32_t w0 = (uint32_t)f2bf_rne(v0.x) | ((uint32_t)f2bf_rne(v0.y) << 16);
        uint32_t w1 = (uint32_t)f2bf_rne(v0.z) | ((uint32_t)f2bf_rne(v0.w) << 16);
        uint32_t w2 = (uint32_t)f2bf_rne(v1.x) | ((uint32_t)f2bf_rne(v1.y) << 16);
        uint32_t w3 = (uint32_t)f2bf_rne(v1.z) | ((uint32_t)f2bf_rne(v1.w) << 16);
        uint4 outB = make_uint4(w0, w1, w2, w3);
        // -2*y exactly in bf16 bits: exp+1 (x2), flip sign (no inf/nan here).
        uint4 outA = make_uint4((w0 + 0x00800080u) ^ 0x80008000u,
                                (w1 + 0x00800080u) ^ 0x80008000u,
                                (w2 + 0x00800080u) ^ 0x80008000u,
                                (w3 + 0x00800080u) ^ 0x80008000u);
        size_t off = (size_t)(b * 2 + u) * 4096 + c8 * 256 + (rloc & 15) * 16;
        *(uint4*)((char*)ybf + off) = outB;
        *(uint4*)((char*)a2y + off) = outA;
        float s = v0.x * v0.x + v0.y * v0.y + v0.z * v0.z + v0.w * v0.w
                + v1.x * v1.x + v1.y * v1.y + v1.z * v1.z + v1.w * v1.w;
        s += __shfl_xor(s, 1); s += __shfl_xor(s, 2);
        s += __shfl_xor(s, 4); s += __shfl_xor(s, 8);
        if (c8 == 0) sq[row] = s;
    }
    __syncthreads();

    // Atomic-free class accumulation: group g (of 4) handles 8 rows into its
    // own LDS copy; thread exclusively owns 2 columns.
    {
        int g = t >> 6, col0 = (t & 63) * 2;
#pragma unroll
        for (int rr = 0; rr < 8; ++rr) {
            int rloc = g * 8 + rr;
            float2 v = *(const float2*)(ys + (size_t)(b * RPB + rloc) * DD + col0);
            int lb = slab[rloc];
            cls[g][lb][col0]     += v.x;
            cls[g][lb][col0 + 1] += v.y;
        }
    }
    __syncthreads();
#pragma unroll
    for (int i = 0; i < 4; ++i) {
        int idx = i * 256 + t;
        float4 s0 = ((const float4*)cls[0])[idx];
        float4 s1 = ((const float4*)cls[1])[idx];
        float4 s2 = ((const float4*)cls[2])[idx];
        float4 s3 = ((const float4*)cls[3])[idx];
        ((float4*)(clspart + (size_t)b * NC * DD))[idx] =
            make_float4((s0.x + s1.x) + (s2.x + s3.x), (s0.y + s1.y) + (s2.y + s3.y),
                        (s0.z + s1.z) + (s2.z + s3.z), (s0.w + s1.w) + (s2.w + s3.w));
    }
    if (b == 0 && t == 0) out[0] = 0.f;
}

// Fused loss. Grid 2112, XCD-swizzled (2112 = 8*264, bijective).
// p < 32: classred -> atomicAdd(out, pos_c*SCALE).
// else: 128x128 tile, bf16 MFMA GEMM with global_load_lds-staged LDS tiles.
// acc = -2*dot; epilogue bound (min acc + min sq_i + min sq_j < 20) gates a
// never-taken slow path that re-verifies candidates EXACTLY from fp32 ys.
__global__ __launch_bounds__(256, 2) void loss_kernel(const unsigned short* __restrict__ a2y,
                                                      const unsigned short* __restrict__ ybf,
                                                      const float* __restrict__ sq,
                                                      const int* __restrict__ lab,
                                                      const float* __restrict__ clspart,
                                                      const float* __restrict__ ys,
                                                      float* __restrict__ out) {
    __shared__ __align__(16) unsigned char sm[65536];  // A: [0,32K), B: [32K,64K)
    int b = blockIdx.x, t = threadIdx.x;
    int p = (b & 7) * 264 + (b >> 3);   // bijective XCD swizzle

    if (p < NC) {
        // ---- classred for class p: pos_c = n_c*ssq_c - ||S_c||^2 ----
        float* sp   = (float*)sm;            // [2][128]
        float* redc = (float*)(sm + 1024);   // [4]
        float* reds = (float*)(sm + 1088);   // [4]
        float* red2 = (float*)(sm + 1152);   // [2]
        int col = t & 127, half = t >> 7;
        float S0 = 0.f, S1 = 0.f, S2 = 0.f, S3 = 0.f;
        const float* cp = clspart + (size_t)half * 128 * NC * DD + p * DD + col;
#pragma unroll 8
        for (int pb = 0; pb < 128; pb += 4) {
            S0 += cp[(size_t)(pb + 0) * NC * DD];
            S1 += cp[(size_t)(pb + 1) * NC * DD];
            S2 += cp[(size_t)(pb + 2) * NC * DD];
            S3 += cp[(size_t)(pb + 3) * NC * DD];
        }
        sp[half * 128 + col] = (S0 + S1) + (S2 + S3);

        float cnt = 0.f, ssq = 0.f;
        for (int rr = t; rr < NN; rr += 256) {
            if (lab[rr] == p) { cnt += 1.f; ssq += sq[rr]; }
        }
#pragma unroll
        for (int off = 32; off >= 1; off >>= 1) {
            cnt += __shfl_down(cnt, off);
            ssq += __shfl_down(ssq, off);
        }
        if ((t & 63) == 0) { redc[t >> 6] = cnt; reds[t >> 6] = ssq; }
        __syncthreads();

        float s2 = 0.f;
        if (t < DD) { float Sc = sp[t] + sp[128 + t]; s2 = Sc * Sc; }
#pragma unroll
        for (int off = 32; off >= 1; off >>= 1) s2 += __shfl_down(s2, off);
        if (t < 128 && (t & 63) == 0) red2[t >> 6] = s2;
        __syncthreads();
        if (t == 0) {
            float c = redc[0] + redc[1] + redc[2] + redc[3];
            float s = reds[0] + reds[1] + reds[2] + reds[3];
            atomicAdd(out, (c * s - (red2[0] + red2[1])) * SCALE);
        }
        return;
    }

    // ---- tile GEMM ----
    int pt = p - NC;
    int q = (NBLK - 1) - pt;
    int r = (int)((sqrtf(8.0f * (float)q + 1.0f) - 1.0f) * 0.5f);
    while (r * (r + 1) / 2 > q) --r;
    while ((r + 1) * (r + 2) / 2 <= q) ++r;
    int bi = (NB - 1) - r;
    int bj = (NB - 1) - (q - r * (r + 1) / 2);
    int i0 = bi * 128, j0 = bj * 128;

    int wave = t >> 6, lane = t & 63;
    int wm = wave >> 1, wn = wave & 1;
    int lr = lane & 15, lg = lane >> 4;

    // Stage 64 KB (A panels + B panels) via async DMA: wave w copies 16 KB
    // linearly; per-lane global src, wave-uniform LDS base (+lane*16 in HW).
    {
        const char* gsrc = (wave < 2)
            ? ((const char*)a2y + (size_t)(i0 >> 4) * 4096 + wave * 16384)
            : ((const char*)ybf + (size_t)(j0 >> 4) * 4096 + (wave - 2) * 16384);
        unsigned lbase = wave * 16384;
#pragma unroll
        for (int it = 0; it < 16; ++it) {
            __builtin_amdgcn_global_load_lds(
                (const uint32_t*)(gsrc + it * 1024 + lane * 16),
                (uint32_t*)(sm + lbase + it * 1024), 16, 0, 0);
        }
    }
    asm volatile("s_waitcnt vmcnt(0)");
    __syncthreads();

    f32x4 acc[4][4];
#pragma unroll
    for (int m = 0; m < 4; ++m)
#pragma unroll
        for (int n = 0; n < 4; ++n) acc[m][n] = (f32x4){0.f, 0.f, 0.f, 0.f};

    const unsigned char* pA = sm + wm * 16384;           // 4 panels x 4 KB
    const unsigned char* pB = sm + 32768 + wn * 16384;
    int foff = lg * 256 + lr * 16;

#pragma unroll
    for (int ks = 0; ks < 4; ++ks) {
        short8 af[4], bf[4];
#pragma unroll
        for (int m = 0; m < 4; ++m) af[m] = *(const short8*)(pA + m * 4096 + ks * 1024 + foff);
#pragma unroll
        for (int n = 0; n < 4; ++n) bf[n] = *(const short8*)(pB + n * 4096 + ks * 1024 + foff);
#pragma unroll
        for (int m = 0; m < 4; ++m)
#pragma unroll
            for (int n = 0; n < 4; ++n)
                acc[m][n] = __builtin_amdgcn_mfma_f32_16x16x32_bf16(af[m], bf[n], acc[m][n], 0, 0, 0);
    }

    // acc[m][n][q] == -2*dot(i,j); d2 = acc + sq_i + sq_j.
    float msi = fminf(sq[i0 + lane * 2], sq[i0 + lane * 2 + 1]);
    float msj = fminf(sq[j0 + lane * 2], sq[j0 + lane * 2 + 1]);
#pragma unroll
    for (int off = 32; off >= 1; off >>= 1) {
        msi = fminf(msi, __shfl_xor(msi, off));
        msj = fminf(msj, __shfl_xor(msj, off));
    }
    float mn = acc[0][0][0];
#pragma unroll
    for (int m = 0; m < 4; ++m)
#pragma unroll
        for (int n = 0; n < 4; ++n)
#pragma unroll
            for (int qq = 0; qq < 4; ++qq) mn = fminf(mn, acc[m][n][qq]);

    if (__any(mn + msi + msj < 20.0f)) {
        // Slow path (never taken for this data): exact re-verification from ys.
        float ns = 0.f;
#pragma unroll
        for (int m = 0; m < 4; ++m)
#pragma unroll
            for (int n = 0; n < 4; ++n)
#pragma unroll
                for (int qq = 0; qq < 4; ++qq) {
                    int i = i0 + wm * 64 + m * 16 + lg * 4 + qq;
                    int j = j0 + wn * 64 + n * 16 + lr;
                    float d2a = acc[m][n][qq] + sq[i] + sq[j];
                    if (d2a < 20.0f && i < j && lab[i] != lab[j]) {
                        float d2e = 0.f;
                        for (int d = 0; d < DD; ++d) {
                            float df = ys[(size_t)i * DD + d] - ys[(size_t)j * DD + d];
                            d2e += df * df;
                        }
                        if (d2e < 1.0f) { float e = 1.0f - sqrtf(d2e); ns += e * e; }
                    }
                }
        if (ns != 0.f) atomicAdd(out, ns * SCALE);
    }
}

extern "C" void kernel_launch(void* const* d_in, const int* in_sizes, int n_in,
                              void* d_out, int out_size, void* d_ws, size_t ws_size,
                              hipStream_t stream) {
    const float* ys = (const float*)d_in[0];
    const int* lab = (const int*)d_in[1];
    float* out = (float*)d_out;

    char* w = (char*)d_ws;
    unsigned short* a2y = (unsigned short*)(w);               // 2 MB (-2y bf16, frag-major)
    unsigned short* ybf = (unsigned short*)(w + 2097152);     // 2 MB (y bf16)
    float* sq       = (float*)(w + 4194304);                  // 32 KB
    float* clspart  = (float*)(w + 4227072);                  // 4 MB

    prep_kernel<<<NPB, 256, 0, stream>>>(ys, lab, a2y, ybf, sq, clspart, out);
    loss_kernel<<<TOTBLK, 256, 0, stream>>>(a2y, ybf, sq, lab, clspart, ys, out);
}